// Round 5
// baseline (479.619 us; speedup 1.0000x reference)
//
#include <hip/hip_runtime.h>
#include <hip/hip_bf16.h>
#include <math.h>

#define NNODES 100000
#define NEDGES 1600000
#define FIN 256
#define HDIM 128
#define NGRAPH 128
#define NCLS 10
#define NEG 0.2f

#define NBUCK 98            // buckets of 1024 dst nodes
#define EPB 4096            // edges per bin_place block
#define EBLK ((NEDGES + EPB - 1) / EPB)   // 391

typedef short bf8 __attribute__((ext_vector_type(8)));
typedef float f4 __attribute__((ext_vector_type(4)));
typedef float f2v __attribute__((ext_vector_type(2)));

__device__ __forceinline__ float lrelu(float x) { return x > 0.f ? x : NEG * x; }

__device__ __forceinline__ unsigned short f2bf(float f) {
  union { float f; unsigned int u; } v; v.f = f;
  unsigned int r = v.u + 0x7fffu + ((v.u >> 16) & 1u);   // round-nearest-even
  return (unsigned short)(r >> 16);
}
__device__ __forceinline__ float bf2f(unsigned short u) {
  union { unsigned int u; float f; } v; v.u = ((unsigned int)u) << 16; return v.f;
}
__device__ __forceinline__ float fast_rcp(float x) {
  float r;
  asm("v_rcp_f32 %0, %1" : "=v"(r) : "v"(x));
  return r;
}
__device__ __forceinline__ unsigned cvt_pk_bf16(float lo, float hi) {
  unsigned r;
  asm("v_cvt_pk_bf16_f32 %0, %1, %2" : "=v"(r) : "v"(lo), "v"(hi));
  return r;
}
// fp8 e4m3 (OCP, gfx950 native) pack/unpack: value payload for the gather.
__device__ __forceinline__ unsigned short pk_fp8(float a, float b) {
  return (unsigned short)__builtin_amdgcn_cvt_pk_fp8_f32(a, b, 0, false);
}
// one-instruction unpack of both heads: v_cvt_pk_f32_fp8 (bytes 0,1 -> 2x f32)
__device__ __forceinline__ f2v pk_unpack_fp8(unsigned p) {
#if __has_builtin(__builtin_amdgcn_cvt_pk_f32_fp8)
  return __builtin_amdgcn_cvt_pk_f32_fp8((int)p, false);
#else
  f2v r;
  r.x = __builtin_amdgcn_cvt_f32_fp8(p, 0);
  r.y = __builtin_amdgcn_cvt_f32_fp8(p, 1);
  return r;
#endif
}

// ---------------- one-shot weight convert+transpose: w[K][128] -> wt[128][K] -
__global__ __launch_bounds__(256) void convert_transpose(const float* __restrict__ w,
                                                         unsigned short* __restrict__ wt,
                                                         int K) {
  int i = blockIdx.x * 256 + threadIdx.x;
  if (i >= K * 128) return;
  int k = i >> 7, n = i & 127;
  wt[n * K + k] = f2bf(w[(size_t)k * 128 + n]);
}

// ---------------- MFMA GEMM: B-resident-in-LDS, barrier-free K-loop ----------
// R4 post-mortem: tile GEMM is latency/BARRIER-bound (MfmaUtil 3.5%, VALU 9%,
// HBM 14%, occ 16%) -- 2 barriers per 32-K-step with everything idle between.
// Key observations: (1) B is tiny (<=64KB) -> stage it WHOLE in LDS (32KB
// K-chunks), (2) the old A staging was an identity LDS round-trip (write
// As[tid], read As[tid]) -> A goes global->VGPR directly in MFMA fragment
// layout. Main loop has ZERO barriers; each wave streams its 128 rows at its
// own pace. Barriers/block: 16 -> 4 (K=256).
// LDS blob layout: Bs[kt*512 + tn*64 + lane] = Bt[(tn*16+(lane&15))*K +
//                  kchunk*128 + kt*32 + ((lane>>4)&3)*8 ..+8]
template<int K, int ABF16>
__global__ __launch_bounds__(256) void gemm_bres(const void* __restrict__ Av,
                                                 const unsigned short* __restrict__ Bt,
                                                 const float* __restrict__ bias,
                                                 unsigned short* __restrict__ Cb,
                                                 unsigned short* __restrict__ Cp,
                                                 const float* __restrict__ a_src,
                                                 const float* __restrict__ a_dst,
                                                 float* __restrict__ o_as,
                                                 float* __restrict__ o_ad,
                                                 int M, int dorelu) {
  __shared__ bf8 Bs[2048];             // 32KB: one 128-wide K-chunk of B
  constexpr int NCH = K / 128;
  int tid = threadIdx.x;
  int wv = tid >> 6, lane = tid & 63;
  int quad = lane >> 4, m16 = lane & 15;
  int row0 = blockIdx.x * 128;

  int rA0 = row0 + wv * 16 + m16; if (rA0 > M - 1) rA0 = M - 1;
  int rA1 = rA0 + 64; if (rA1 > M - 1) rA1 = M - 1;
  int cOff = quad * 8;

  auto cvt8 = [&](float4 a, float4 b) -> bf8 {
    union { bf8 v; unsigned u[4]; } r;
    r.u[0] = cvt_pk_bf16(a.x, a.y); r.u[1] = cvt_pk_bf16(a.z, a.w);
    r.u[2] = cvt_pk_bf16(b.x, b.y); r.u[3] = cvt_pk_bf16(b.z, b.w);
    return r.v;
  };

  f4 acc[16];
#pragma unroll
  for (int b = 0; b < 16; ++b) acc[b] = (f4){0.f, 0.f, 0.f, 0.f};

  for (int ch = 0; ch < NCH; ++ch) {
    if (ch) __syncthreads();           // protect Bs overwrite
    // cooperative stage of 32KB B-chunk (2048 blobs, 8 per thread)
#pragma unroll
    for (int jj = 0; jj < 8; ++jj) {
      int j = jj * 256 + tid;
      int n = ((j >> 6) & 7) * 16 + (j & 15);
      int k = ch * 128 + (j >> 9) * 32 + ((j >> 4) & 3) * 8;
      Bs[j] = *reinterpret_cast<const bf8*>(&Bt[(size_t)n * K + k]);
    }
    __syncthreads();
    // barrier-free compute over this K-chunk
#pragma unroll
    for (int kt = 0; kt < 4; ++kt) {
      int kb = ch * 128 + kt * 32;
      bf8 a0, a1;
      if (ABF16) {
        a0 = *reinterpret_cast<const bf8*>((const unsigned short*)Av + (size_t)rA0 * K + kb + cOff);
        a1 = *reinterpret_cast<const bf8*>((const unsigned short*)Av + (size_t)rA1 * K + kb + cOff);
      } else {
        const float* p0 = (const float*)Av + (size_t)rA0 * K + kb + cOff;
        const float* p1 = (const float*)Av + (size_t)rA1 * K + kb + cOff;
        float4 x0 = *reinterpret_cast<const float4*>(p0);
        float4 x1 = *reinterpret_cast<const float4*>(p0 + 4);
        float4 y0 = *reinterpret_cast<const float4*>(p1);
        float4 y1 = *reinterpret_cast<const float4*>(p1 + 4);
        a0 = cvt8(x0, x1);
        a1 = cvt8(y0, y1);
      }
#pragma unroll
      for (int tn = 0; tn < 8; ++tn) {
        bf8 bfm = Bs[kt * 512 + tn * 64 + lane];
        acc[tn]     = __builtin_amdgcn_mfma_f32_16x16x32_bf16(a0, bfm, acc[tn], 0, 0, 0);
        acc[8 + tn] = __builtin_amdgcn_mfma_f32_16x16x32_bf16(a1, bfm, acc[8 + tn], 0, 0, 0);
      }
    }
  }

  if (Cp) {
    if (a_src) {
      float aS[8], aD[8];
#pragma unroll
      for (int tn = 0; tn < 4; ++tn) {
        aS[tn]     = a_src[tn * 16 + m16];
        aS[tn + 4] = a_src[64 + tn * 16 + m16];
        aD[tn]     = a_dst[tn * 16 + m16];
        aD[tn + 4] = a_dst[64 + tn * 16 + m16];
      }
#pragma unroll
      for (int mt = 0; mt < 2; ++mt) {
#pragma unroll
        for (int r = 0; r < 4; ++r) {
          int row = row0 + mt * 64 + wv * 16 + quad * 4 + r;
          float ps0 = 0.f, ps1 = 0.f, pd0 = 0.f, pd1 = 0.f;
#pragma unroll
          for (int tn = 0; tn < 4; ++tn) {
            float v0 = acc[mt * 8 + tn][r], v1 = acc[mt * 8 + tn + 4][r];
            ps0 = fmaf(v0, aS[tn], ps0);
            ps1 = fmaf(v1, aS[tn + 4], ps1);
            pd0 = fmaf(v0, aD[tn], pd0);
            pd1 = fmaf(v1, aD[tn + 4], pd1);
          }
#pragma unroll
          for (int o = 8; o; o >>= 1) {
            ps0 += __shfl_xor(ps0, o); ps1 += __shfl_xor(ps1, o);
            pd0 += __shfl_xor(pd0, o); pd1 += __shfl_xor(pd1, o);
          }
          if (m16 == 0 && row < M) {
            o_as[2 * row] = ps0; o_as[2 * row + 1] = ps1;
            o_ad[2 * row] = pd0; o_ad[2 * row + 1] = pd1;
          }
        }
      }
    }
#pragma unroll
    for (int mt = 0; mt < 2; ++mt)
#pragma unroll
      for (int tn = 0; tn < 4; ++tn)
#pragma unroll
        for (int r = 0; r < 4; ++r) {
          int row = row0 + mt * 64 + wv * 16 + quad * 4 + r;
          if (row < M) {
            Cp[(size_t)row * 64 + tn * 16 + m16] =
                pk_fp8(acc[mt * 8 + tn][r], acc[mt * 8 + tn + 4][r]);
          }
        }
  } else {
#pragma unroll
    for (int mt = 0; mt < 2; ++mt)
#pragma unroll
      for (int tn = 0; tn < 8; ++tn) {
        float bv = bias ? bias[tn * 16 + m16] : 0.f;
#pragma unroll
        for (int r = 0; r < 4; ++r) {
          int row = row0 + mt * 64 + wv * 16 + quad * 4 + r;
          if (row < M) {
            float v = acc[mt * 8 + tn][r] + bv;
            if (dorelu) v = fmaxf(v, 0.f);
            Cb[(size_t)row * 128 + tn * 16 + m16] = f2bf(v);
          }
        }
      }
  }
}

// ---------------- graph boundaries (batch is sorted) -------------------------
__global__ void find_starts(const int* __restrict__ batch, int* __restrict__ gstart) {
  int g = threadIdx.x;
  if (g > NGRAPH) return;
  if (g == NGRAPH) { gstart[g] = NNODES; return; }
  int lo = 0, hi = NNODES;
  while (lo < hi) { int mid = (lo + hi) >> 1; if (batch[mid] < g) lo = mid + 1; else hi = mid; }
  gstart[g] = lo;
}

// ======== CSR build, bucketed two-phase (no random global atomics) ==========
__global__ __launch_bounds__(256) void bin_count(const int* __restrict__ edst,
                                                 int* __restrict__ blockHist) {
  __shared__ int hist[NBUCK];
  int t = threadIdx.x, blk = blockIdx.x;
  if (t < NBUCK) hist[t] = 0;
  __syncthreads();
  int e0 = blk * EPB;
#pragma unroll
  for (int it = 0; it < EPB / 256; ++it) {
    int e = e0 + it * 256 + t;
    if (e < NEDGES) atomicAdd(&hist[((unsigned)edst[e]) >> 10], 1);
  }
  __syncthreads();
  if (t < NBUCK) blockHist[blk * NBUCK + t] = hist[t];
}

__global__ __launch_bounds__(512) void colscan(const int* __restrict__ blockHist,
                                               int* __restrict__ blockBaseCol,
                                               int* __restrict__ bucket_total) {
  __shared__ int s[512];
  int b = blockIdx.x, t = threadIdx.x;
  int v = (t < EBLK) ? blockHist[t * NBUCK + b] : 0;
  s[t] = v;
  __syncthreads();
  for (int off = 1; off < 512; off <<= 1) {
    int u = (t >= off) ? s[t - off] : 0;
    __syncthreads();
    s[t] += u;
    __syncthreads();
  }
  if (t < EBLK) blockBaseCol[b * EBLK + t] = s[t] - v;
  if (t == 511) bucket_total[b] = s[511];
}

__global__ __launch_bounds__(128) void bscan(const int* __restrict__ bucket_total,
                                             int* __restrict__ bucket_ptr) {
  __shared__ int s[128];
  int t = threadIdx.x;
  int v = (t < NBUCK) ? bucket_total[t] : 0;
  s[t] = v;
  __syncthreads();
  for (int off = 1; off < 128; off <<= 1) {
    int u = (t >= off) ? s[t - off] : 0;
    __syncthreads();
    s[t] += u;
    __syncthreads();
  }
  if (t < NBUCK) bucket_ptr[t] = s[t] - v;
  if (t == 127) bucket_ptr[NBUCK] = s[127];
}

// staging entry: (dst_local_10bits << 17) | src_17bits  (NNODES < 2^17)
__global__ __launch_bounds__(512) void bin_place(const int* __restrict__ esrc,
                                                 const int* __restrict__ edst,
                                                 const int* __restrict__ blockBaseCol,
                                                 const int* __restrict__ bucket_ptr,
                                                 unsigned* __restrict__ stagingG) {
  __shared__ int hist[NBUCK + 1], lbase[NBUCK + 1], lcur[NBUCK + 1], cbase[NBUCK];
  __shared__ int tmp[128];
  __shared__ uint2 st[EPB];
  int t = threadIdx.x, blk = blockIdx.x;
  if (t < NBUCK + 1) hist[t] = 0;
  __syncthreads();
  int e0 = blk * EPB;
#pragma unroll
  for (int it = 0; it < EPB / 512; ++it) {
    int e = e0 + it * 512 + t;
    int b = NBUCK;
    if (e < NEDGES) b = ((unsigned)edst[e]) >> 10;
    atomicAdd(&hist[b], 1);
  }
  __syncthreads();
  if (t < 128) tmp[t] = (t < NBUCK + 1) ? hist[t] : 0;
  __syncthreads();
  for (int off = 1; off < 128; off <<= 1) {
    int u = 0;
    if (t < 128 && t >= off) u = tmp[t - off];
    __syncthreads();
    if (t < 128) tmp[t] += u;
    __syncthreads();
  }
  if (t < NBUCK + 1) { int ex = tmp[t] - hist[t]; lbase[t] = ex; lcur[t] = ex; }
  if (t < NBUCK) cbase[t] = bucket_ptr[t] + blockBaseCol[t * EBLK + blk];
  __syncthreads();
#pragma unroll
  for (int it = 0; it < EPB / 512; ++it) {
    int e = e0 + it * 512 + t;
    unsigned s = 0, d = 0xFFFFFFFFu;
    if (e < NEDGES) { s = (unsigned)esrc[e]; d = (unsigned)edst[e]; }
    int b = (d == 0xFFFFFFFFu) ? NBUCK : (int)(d >> 10);
    int slot = atomicAdd(&lcur[b], 1);
    st[slot] = make_uint2(s, d);
  }
  __syncthreads();
  for (int i = t; i < EPB; i += 512) {
    uint2 ed = st[i];
    if (ed.y == 0xFFFFFFFFu) continue;
    int b = (int)(ed.y >> 10);
    stagingG[cbase[b] + (i - lbase[b])] = ((ed.y & 1023u) << 17) | ed.x;
  }
}

// fused: per-bucket degree histogram + LDS scan -> row_ptr, then scatter
__global__ __launch_bounds__(1024) void bucket_csr_fused(const unsigned* __restrict__ stagingG,
                                                         const int* __restrict__ bucket_ptr,
                                                         int* __restrict__ row_ptr,
                                                         int* __restrict__ colv) {
  __shared__ int dl[1024];
  __shared__ int cur[1024];
  int b = blockIdx.x, t = threadIdx.x;
  dl[t] = 0;
  __syncthreads();
  int s0 = bucket_ptr[b], s1 = bucket_ptr[b + 1];
  for (int j = s0 + t; j < s1; j += 1024)
    atomicAdd(&dl[stagingG[j] >> 17], 1);
  __syncthreads();
  int myDeg = dl[t];
  for (int off = 1; off < 1024; off <<= 1) {
    int u = (t >= off) ? dl[t - off] : 0;
    __syncthreads();
    dl[t] += u;
    __syncthreads();
  }
  int rp = s0 + dl[t] - myDeg;
  cur[t] = rp;
  int n = (b << 10) + t;
  if (n < NNODES) row_ptr[n] = rp;
  if (n == NNODES - 1) row_ptr[NNODES] = rp + myDeg;
  __syncthreads();
  for (int j = s0 + t; j < s1; j += 1024) {
    unsigned v = stagingG[j];
    int pos = atomicAdd(&cur[v >> 17], 1);
    colv[pos] = (int)(v & 0x1FFFFu);
  }
}

// ---------------- softmax aggregation: one wave per dst node -----------------
// fp8 payload (128B/row); weights broadcast via wave-private LDS ds_read_b64;
// both heads unpacked with one v_cvt_pk_f32_fp8; gather unrolled 8-deep.
__global__ __launch_bounds__(256) void aggregate(const unsigned short* __restrict__ hwb,
                                                 const float* __restrict__ a_s,
                                                 const float* __restrict__ a_d,
                                                 const int* __restrict__ row_ptr,
                                                 const int* __restrict__ colv,
                                                 const float* __restrict__ bias,
                                                 unsigned short* __restrict__ out) {
  __shared__ float2 wsh[256];           // 4 waves x 64 (w0,w1) entries
  int i = (blockIdx.x * 256 + threadIdx.x) >> 6;
  int lane = threadIdx.x & 63;
  if (i >= NNODES) return;
  i = __builtin_amdgcn_readfirstlane(i);
  int wbase = (threadIdx.x >> 6) * 64;

  float ad0 = a_d[2 * i], ad1 = a_d[2 * i + 1];
  int start = row_ptr[i], end = row_ptr[i + 1];
  int deg = end - start;
  float ws0 = __expf(lrelu(a_s[2 * i] + ad0));      // self edge
  float ws1 = __expf(lrelu(a_s[2 * i + 1] + ad1));

  int sl = 0; float w0l = 0.f, w1l = 0.f;
  if (lane < deg) {
    sl = colv[start + lane];
    float2 av = *reinterpret_cast<const float2*>(&a_s[2 * sl]);
    w0l = __expf(lrelu(av.x + ad0));
    w1l = __expf(lrelu(av.y + ad1));
  }
  wsh[wbase + lane] = make_float2(w0l, w1l);   // wave-private, no barrier
  float d0 = w0l, d1 = w1l;
  for (int o = 32; o; o >>= 1) { d0 += __shfl_xor(d0, o); d1 += __shfl_xor(d1, o); }
  float den0 = d0 + ws0, den1 = d1 + ws1;

  unsigned ps = hwb[(size_t)i * 64 + lane];
  f2v pv = pk_unpack_fp8(ps);
  float acc0 = ws0 * pv.x, acc1 = ws1 * pv.y;

  int dmin = deg < 64 ? deg : 64;
  int t = 0;
#define GSTEP(T)                                                               \
  {                                                                            \
    int s = __builtin_amdgcn_readlane(sl, (T));                                \
    unsigned q = hwb[(size_t)s * 64 + lane];                                   \
    float2 w = wsh[wbase + (T)];            /* ds_read_b64 broadcast */        \
    f2v xv = pk_unpack_fp8(q);                                                 \
    acc0 = fmaf(w.x, xv.x, acc0);                                              \
    acc1 = fmaf(w.y, xv.y, acc1);                                              \
  }
  for (; t + 8 <= dmin; t += 8) {
    GSTEP(t);     GSTEP(t + 1); GSTEP(t + 2); GSTEP(t + 3);
    GSTEP(t + 4); GSTEP(t + 5); GSTEP(t + 6); GSTEP(t + 7);
  }
  for (; t < dmin; ++t) { GSTEP(t); }
#undef GSTEP

  for (int j = start + 64; j < end; ++j) {   // rare overflow path (deg > 64)
    int s = colv[j];
    float2 av = *reinterpret_cast<const float2*>(&a_s[2 * s]);
    float w0 = __expf(lrelu(av.x + ad0));
    float w1 = __expf(lrelu(av.y + ad1));
    den0 += w0; den1 += w1;
    unsigned q = hwb[(size_t)s * 64 + lane];
    f2v xv = pk_unpack_fp8(q);
    acc0 = fmaf(w0, xv.x, acc0);
    acc1 = fmaf(w1, xv.y, acc1);
  }

  float r0 = fast_rcp(den0), r1 = fast_rcp(den1);
  float o0 = fmaxf(acc0 * r0 + bias[lane], 0.f);
  float o1 = fmaxf(acc1 * r1 + bias[64 + lane], 0.f);
  unsigned pk = cvt_pk_bf16(o0, o1);
  out[(size_t)i * 128 + lane]      = (unsigned short)pk;
  out[(size_t)i * 128 + 64 + lane] = (unsigned short)(pk >> 16);
}

// ---------------- per-graph pooling, node-parallel (bf16 input) --------------
#define SEG_CHUNK 128
__global__ __launch_bounds__(128) void seg_sum_fast(const unsigned short* __restrict__ h,
                                                    const int* __restrict__ batch,
                                                    const int* __restrict__ gstart,
                                                    float* __restrict__ reprs) {
  int n0 = blockIdx.x * SEG_CHUNK;
  if (n0 >= NNODES) return;
  int nend = n0 + SEG_CHUNK; if (nend > NNODES) nend = NNODES;
  int tid = threadIdx.x;
  int r = n0;
  while (r < nend) {
    int g = batch[r];
    int segend = gstart[g + 1]; if (segend > nend) segend = nend;
    float a0 = 0.f, a1 = 0.f, a2 = 0.f, a3 = 0.f;
    for (; r + 3 < segend; r += 4) {
      a0 += bf2f(h[(size_t)r * 128 + tid]);
      a1 += bf2f(h[(size_t)(r + 1) * 128 + tid]);
      a2 += bf2f(h[(size_t)(r + 2) * 128 + tid]);
      a3 += bf2f(h[(size_t)(r + 3) * 128 + tid]);
    }
    for (; r < segend; ++r) a0 += bf2f(h[(size_t)r * 128 + tid]);
    atomicAdd(&reprs[g * 128 + tid], (a0 + a1) + (a2 + a3));
  }
}

// ---------------- head MLP + log_softmax -------------------------------------
__global__ __launch_bounds__(128) void head_kernel(const float* __restrict__ reprs,
                                                   const float* __restrict__ pw1,
                                                   const float* __restrict__ pb1,
                                                   const float* __restrict__ pw2,
                                                   const float* __restrict__ pb2,
                                                   float* __restrict__ out) {
  __shared__ float r[128], t1[128], z[NCLS];
  int g = blockIdx.x, tid = threadIdx.x;
  r[tid] = reprs[g * 128 + tid];
  __syncthreads();
  float acc = pb1[tid];
  for (int k = 0; k < 128; ++k) acc = fmaf(r[k], pw1[k * 128 + tid], acc);
  t1[tid] = fmaxf(acc, 0.f);
  __syncthreads();
  if (tid < NCLS) {
    float zz = pb2[tid];
    for (int k = 0; k < 128; ++k) zz = fmaf(t1[k], pw2[k * NCLS + tid], zz);
    z[tid] = zz;
  }
  __syncthreads();
  if (tid == 0) {
    float mx = -1e30f;
    for (int c = 0; c < NCLS; ++c) mx = fmaxf(mx, z[c]);
    float s = 0.f;
    for (int c = 0; c < NCLS; ++c) s += expf(z[c] - mx);
    float ls = logf(s) + mx;
    for (int c = 0; c < NCLS; ++c) out[g * NCLS + c] = z[c] - ls;
  }
}

extern "C" void kernel_launch(void* const* d_in, const int* in_sizes, int n_in,
                              void* d_out, int out_size, void* d_ws, size_t ws_size,
                              hipStream_t stream) {
  const float* x     = (const float*)d_in[0];
  const int*   eidx  = (const int*)d_in[1];
  const int*   batch = (const int*)d_in[2];
  const float* pre_w = (const float*)d_in[3];
  const float* pre_b = (const float*)d_in[4];
  const float* w1    = (const float*)d_in[5];
  const float* asrc1 = (const float*)d_in[6];
  const float* adst1 = (const float*)d_in[7];
  const float* b1    = (const float*)d_in[8];
  const float* w2    = (const float*)d_in[9];
  const float* asrc2 = (const float*)d_in[10];
  const float* adst2 = (const float*)d_in[11];
  const float* b2    = (const float*)d_in[12];
  const float* pw1   = (const float*)d_in[13];
  const float* pb1   = (const float*)d_in[14];
  const float* pw2   = (const float*)d_in[15];
  const float* pb2   = (const float*)d_in[16];
  float* out = (float*)d_out;

  const int* esrc = eidx;
  const int* edst = eidx + NEDGES;

  char* wsp = (char*)d_ws;
  size_t off = 0;
  auto alloc = [&](size_t bytes) -> void* {
    void* p = wsp + off;
    off += (bytes + 255) & ~(size_t)255;
    return p;
  };
  unsigned short* hb  = (unsigned short*)alloc((size_t)NNODES * 128 * 2);
  unsigned short* hwb = (unsigned short*)alloc((size_t)NNODES * 64 * 2);   // fp8 pairs
  float* a_s         = (float*)alloc((size_t)NNODES * 2 * 4);
  float* a_d         = (float*)alloc((size_t)NNODES * 2 * 4);
  float* reprs       = (float*)alloc((size_t)NGRAPH * 128 * 4);
  int* gstart        = (int*)alloc((NGRAPH + 1) * 4);
  int* row_ptr       = (int*)alloc(((size_t)NNODES + 1) * 4);
  int* colv          = (int*)alloc((size_t)NEDGES * 4);
  unsigned short* wt_pre = (unsigned short*)alloc((size_t)128 * FIN * 2);
  unsigned short* wt1    = (unsigned short*)alloc((size_t)128 * HDIM * 2);
  unsigned short* wt2    = (unsigned short*)alloc((size_t)128 * HDIM * 2);
  int* blockHist     = (int*)alloc((size_t)EBLK * NBUCK * 4);
  int* blockBaseCol  = (int*)alloc((size_t)NBUCK * EBLK * 4);
  int* bucket_total  = (int*)alloc(NBUCK * 4);
  int* bucket_ptr    = (int*)alloc((NBUCK + 1) * 4);
  unsigned* stagingG = (unsigned*)alloc((size_t)NEDGES * 4);

  int wb = NNODES / 4;             // wave-per-node kernels: 256 thr = 4 waves
  int sb = (NNODES + SEG_CHUNK - 1) / SEG_CHUNK;
  int gb = (NNODES + 127) / 128;   // 782 GEMM blocks (128-row tiles)

  // one-shot weight conversion (bf16, transposed)
  convert_transpose<<<(FIN * 128 + 255) / 256, 256, 0, stream>>>(pre_w, wt_pre, FIN);
  convert_transpose<<<(HDIM * 128 + 255) / 256, 256, 0, stream>>>(w1, wt1, HDIM);
  convert_transpose<<<(HDIM * 128 + 255) / 256, 256, 0, stream>>>(w2, wt2, HDIM);

  // graph boundaries + zeroed pooling accumulator
  hipMemsetAsync(reprs, 0, (size_t)NGRAPH * 128 * 4, stream);
  find_starts<<<1, 256, 0, stream>>>(batch, gstart);

  // bucketed CSR build (packed 4B staging; fused deg-scan + scatter)
  bin_count<<<EBLK, 256, 0, stream>>>(edst, blockHist);
  colscan<<<NBUCK, 512, 0, stream>>>(blockHist, blockBaseCol, bucket_total);
  bscan<<<1, 128, 0, stream>>>(bucket_total, bucket_ptr);
  bin_place<<<EBLK, 512, 0, stream>>>(esrc, edst, blockBaseCol, bucket_ptr, stagingG);
  bucket_csr_fused<<<NBUCK, 1024, 0, stream>>>(stagingG, bucket_ptr, row_ptr, colv);

  // pre layer: h0 = relu(x @ pre_w + pre_b)  (bf16 h)
  gemm_bres<FIN, 0><<<gb, 256, 0, stream>>>(x, wt_pre, pre_b, hb, nullptr,
                                            nullptr, nullptr, nullptr, nullptr, NNODES, 1);
  seg_sum_fast<<<sb, 128, 0, stream>>>(hb, batch, gstart, reprs);

  // GAT layer 1 (bf16 A; alpha fused into GEMM epilogue; fp8 value payload)
  gemm_bres<HDIM, 1><<<gb, 256, 0, stream>>>(hb, wt1, nullptr, nullptr, hwb,
                                             asrc1, adst1, a_s, a_d, NNODES, 0);
  aggregate<<<wb, 256, 0, stream>>>(hwb, a_s, a_d, row_ptr, colv, b1, hb);
  seg_sum_fast<<<sb, 128, 0, stream>>>(hb, batch, gstart, reprs);

  // GAT layer 2
  gemm_bres<HDIM, 1><<<gb, 256, 0, stream>>>(hb, wt2, nullptr, nullptr, hwb,
                                             asrc2, adst2, a_s, a_d, NNODES, 0);
  aggregate<<<wb, 256, 0, stream>>>(hwb, a_s, a_d, row_ptr, colv, b2, hb);
  seg_sum_fast<<<sb, 128, 0, stream>>>(hb, batch, gstart, reprs);

  // head
  head_kernel<<<NGRAPH, 128, 0, stream>>>(reprs, pw1, pb1, pw2, pb2, out);
}

// Round 6
// 470.290 us; speedup vs baseline: 1.0198x; 1.0198x over previous
//
#include <hip/hip_runtime.h>
#include <hip/hip_bf16.h>
#include <math.h>

#define NNODES 100000
#define NEDGES 1600000
#define FIN 256
#define HDIM 128
#define NGRAPH 128
#define NCLS 10
#define NEG 0.2f

#define NBUCK 98            // buckets of 1024 dst nodes
#define EPB 4096            // edges per bin_place block
#define EBLK ((NEDGES + EPB - 1) / EPB)   // 391

typedef short bf8 __attribute__((ext_vector_type(8)));
typedef float f4 __attribute__((ext_vector_type(4)));
typedef float f2v __attribute__((ext_vector_type(2)));

__device__ __forceinline__ float lrelu(float x) { return x > 0.f ? x : NEG * x; }

__device__ __forceinline__ unsigned short f2bf(float f) {
  union { float f; unsigned int u; } v; v.f = f;
  unsigned int r = v.u + 0x7fffu + ((v.u >> 16) & 1u);   // round-nearest-even
  return (unsigned short)(r >> 16);
}
__device__ __forceinline__ float bf2f(unsigned short u) {
  union { unsigned int u; float f; } v; v.u = ((unsigned int)u) << 16; return v.f;
}
__device__ __forceinline__ float fast_rcp(float x) {
  float r;
  asm("v_rcp_f32 %0, %1" : "=v"(r) : "v"(x));
  return r;
}
__device__ __forceinline__ unsigned cvt_pk_bf16(float lo, float hi) {
  unsigned r;
  asm("v_cvt_pk_bf16_f32 %0, %1, %2" : "=v"(r) : "v"(lo), "v"(hi));
  return r;
}
// fp8 e4m3 (OCP, gfx950 native) pack/unpack: value payload for the gather.
__device__ __forceinline__ unsigned short pk_fp8(float a, float b) {
  return (unsigned short)__builtin_amdgcn_cvt_pk_fp8_f32(a, b, 0, false);
}
// one-instruction unpack of both heads: v_cvt_pk_f32_fp8 (bytes 0,1 -> 2x f32)
__device__ __forceinline__ f2v pk_unpack_fp8(unsigned p) {
#if __has_builtin(__builtin_amdgcn_cvt_pk_f32_fp8)
  return __builtin_amdgcn_cvt_pk_f32_fp8((int)p, false);
#else
  f2v r;
  r.x = __builtin_amdgcn_cvt_f32_fp8(p, 0);
  r.y = __builtin_amdgcn_cvt_f32_fp8(p, 1);
  return r;
#endif
}

// ---------------- one-shot weight convert+transpose: w[K][128] -> wt[128][K] -
__global__ __launch_bounds__(256) void convert_transpose(const float* __restrict__ w,
                                                         unsigned short* __restrict__ wt,
                                                         int K) {
  int i = blockIdx.x * 256 + threadIdx.x;
  if (i >= K * 128) return;
  int k = i >> 7, n = i & 127;
  wt[n * K + k] = f2bf(w[(size_t)k * 128 + n]);
}

// ---------------- MFMA GEMM: contiguous-stage, 64x128 tile -------------------
// R3-R5 post-mortem: every variant loaded A in MFMA-fragment order (each lane
// a 16B piece of a DIFFERENT row -> 64B segments on a power-of-2 row stride).
// That strided small-segment stream hotspots HBM channels/L2 banks: all GEMMs
// sat ~95% idle regardless of tile/barrier structure. Fix: stage A with
// INSTRUCTION-CONTIGUOUS sweeps (wave covers a contiguous 1KB+ span per load),
// convert f32->bf16 in flight, scatter into MFMA blob layout in LDS with a
// ^(kt<<4) XOR (else the one-row-per-wave scatter is a 16-way bank conflict).
// A staged whole; B (<=64KB, L2-resident) staged in 32KB chunks. K=128: ONE
// barrier total. All stage loads independent -> deep MLP per wave.
// Blob layout: A[kt][mtile][lane] 16B = A[row0+mtile*16+(lane&15)]
//              [kt*32+(lane>>4)*8 ..+8]; B[ktl][tn][lane] likewise.
template<int K, int ABF16>
__global__ __launch_bounds__(256) void gemm_cstage(const void* __restrict__ Av,
                                                   const unsigned short* __restrict__ Bt,
                                                   const float* __restrict__ bias,
                                                   unsigned short* __restrict__ Cb,
                                                   unsigned short* __restrict__ Cp,
                                                   const float* __restrict__ a_src,
                                                   const float* __restrict__ a_dst,
                                                   float* __restrict__ o_as,
                                                   float* __restrict__ o_ad,
                                                   int M, int dorelu) {
  constexpr int NKT = K / 32;                       // 8 (pre) / 4 (layer)
  __shared__ alignas(16) char AL[NKT * 256 * 16];   // 32KB / 16KB
  __shared__ alignas(16) char BL[4 * 512 * 16];     // 32KB B chunk
  int tid = threadIdx.x;
  int wv = tid >> 6, lane = tid & 63;
  int quad = lane >> 4, m16 = lane & 15;
  int row0 = blockIdx.x * 64;

  // ---- stage A (whole, contiguous global sweep) ----
  if (ABF16) {
    const unsigned short* A = (const unsigned short*)Av;
    constexpr int UPR = K / 8;                      // 16B units per row
#pragma unroll
    for (int i = 0; i < (64 * UPR) / 256; ++i) {
      int m = i * 256 + tid;
      int row = m / UPR;
      int u = m & (UPR - 1);
      int rr = row0 + row; if (rr > M - 1) rr = M - 1;
      bf8 v = *(const bf8*)&A[(size_t)rr * K + u * 8];
      int kt = u >> 2, q = u & 3;
      int dst = (((kt * 256) + (row >> 4) * 64 + q * 16 + (row & 15)) * 16) ^ ((kt & 7) << 4);
      *(bf8*)(AL + dst) = v;
    }
  } else {
    const float* A = (const float*)Av;
    constexpr int UPRF = K / 4;                     // 16B units per row
#pragma unroll
    for (int i = 0; i < (64 * UPRF) / 256; ++i) {
      int m = i * 256 + tid;
      int row = m / UPRF;
      int u = m & (UPRF - 1);
      int rr = row0 + row; if (rr > M - 1) rr = M - 1;
      float4 v = *(const float4*)&A[(size_t)rr * K + u * 4];
      int kt = u >> 3, q = (u >> 1) & 3;
      int dst = ((kt * 256 + (row >> 4) * 64 + q * 16 + (row & 15)) * 16 + (u & 1) * 8) ^ ((kt & 7) << 4);
      uint2 w; w.x = cvt_pk_bf16(v.x, v.y); w.y = cvt_pk_bf16(v.z, v.w);
      *(uint2*)(AL + dst) = w;
    }
  }

  // ---- stage one 32KB B chunk (128 n-rows x 128 K) ----
  auto stageB = [&](int ch) {
#pragma unroll
    for (int i = 0; i < 8; ++i) {
      int m = i * 256 + tid;
      int nrow = m >> 4;
      int u = m & 15;
      bf8 v = *(const bf8*)&Bt[(size_t)nrow * K + ch * 128 + u * 8];
      int ktl = u >> 2;
      int dst = ((ktl * 512 + (nrow >> 4) * 64 + (u & 3) * 16 + (nrow & 15)) * 16) ^ (ktl << 4);
      *(bf8*)(BL + dst) = v;
    }
  };

  f4 acc[8];
#pragma unroll
  for (int b = 0; b < 8; ++b) acc[b] = (f4){0.f, 0.f, 0.f, 0.f};

  stageB(0);
  __syncthreads();
  constexpr int NCH = K / 128;
#pragma unroll
  for (int ch = 0; ch < NCH; ++ch) {
    if (ch) { __syncthreads(); stageB(ch); __syncthreads(); }
#pragma unroll
    for (int ktl = 0; ktl < 4; ++ktl) {
      int kt = ch * 4 + ktl;
      bf8 af = *(const bf8*)(AL + ((((kt * 256) + wv * 64 + lane) * 16) ^ ((kt & 7) << 4)));
#pragma unroll
      for (int tn = 0; tn < 8; ++tn) {
        bf8 bm = *(const bf8*)(BL + (((ktl * 512 + tn * 64 + lane) * 16) ^ (ktl << 4)));
        acc[tn] = __builtin_amdgcn_mfma_f32_16x16x32_bf16(af, bm, acc[tn], 0, 0, 0);
      }
    }
  }

  if (Cp) {
    if (a_src) {
      float aS[8], aD[8];
#pragma unroll
      for (int tn = 0; tn < 4; ++tn) {
        aS[tn]     = a_src[tn * 16 + m16];
        aS[tn + 4] = a_src[64 + tn * 16 + m16];
        aD[tn]     = a_dst[tn * 16 + m16];
        aD[tn + 4] = a_dst[64 + tn * 16 + m16];
      }
#pragma unroll
      for (int r = 0; r < 4; ++r) {
        int row = row0 + wv * 16 + quad * 4 + r;
        float ps0 = 0.f, ps1 = 0.f, pd0 = 0.f, pd1 = 0.f;
#pragma unroll
        for (int tn = 0; tn < 4; ++tn) {
          float v0 = acc[tn][r], v1 = acc[tn + 4][r];
          ps0 = fmaf(v0, aS[tn], ps0);
          ps1 = fmaf(v1, aS[tn + 4], ps1);
          pd0 = fmaf(v0, aD[tn], pd0);
          pd1 = fmaf(v1, aD[tn + 4], pd1);
        }
#pragma unroll
        for (int o = 8; o; o >>= 1) {
          ps0 += __shfl_xor(ps0, o); ps1 += __shfl_xor(ps1, o);
          pd0 += __shfl_xor(pd0, o); pd1 += __shfl_xor(pd1, o);
        }
        if (m16 == 0 && row < M) {
          o_as[2 * row] = ps0; o_as[2 * row + 1] = ps1;
          o_ad[2 * row] = pd0; o_ad[2 * row + 1] = pd1;
        }
      }
    }
#pragma unroll
    for (int tn = 0; tn < 4; ++tn)
#pragma unroll
      for (int r = 0; r < 4; ++r) {
        int row = row0 + wv * 16 + quad * 4 + r;
        if (row < M) {
          Cp[(size_t)row * 64 + tn * 16 + m16] = pk_fp8(acc[tn][r], acc[tn + 4][r]);
        }
      }
  } else {
#pragma unroll
    for (int tn = 0; tn < 8; ++tn) {
      float bv = bias ? bias[tn * 16 + m16] : 0.f;
#pragma unroll
      for (int r = 0; r < 4; ++r) {
        int row = row0 + wv * 16 + quad * 4 + r;
        if (row < M) {
          float v = acc[tn][r] + bv;
          if (dorelu) v = fmaxf(v, 0.f);
          Cb[(size_t)row * 128 + tn * 16 + m16] = f2bf(v);
        }
      }
    }
  }
}

// ---------------- graph boundaries (batch is sorted) -------------------------
__global__ void find_starts(const int* __restrict__ batch, int* __restrict__ gstart) {
  int g = threadIdx.x;
  if (g > NGRAPH) return;
  if (g == NGRAPH) { gstart[g] = NNODES; return; }
  int lo = 0, hi = NNODES;
  while (lo < hi) { int mid = (lo + hi) >> 1; if (batch[mid] < g) lo = mid + 1; else hi = mid; }
  gstart[g] = lo;
}

// ======== CSR build, bucketed two-phase (no random global atomics) ==========
__global__ __launch_bounds__(256) void bin_count(const int* __restrict__ edst,
                                                 int* __restrict__ blockHist) {
  __shared__ int hist[NBUCK];
  int t = threadIdx.x, blk = blockIdx.x;
  if (t < NBUCK) hist[t] = 0;
  __syncthreads();
  int e0 = blk * EPB;
#pragma unroll
  for (int it = 0; it < EPB / 256; ++it) {
    int e = e0 + it * 256 + t;
    if (e < NEDGES) atomicAdd(&hist[((unsigned)edst[e]) >> 10], 1);
  }
  __syncthreads();
  if (t < NBUCK) blockHist[blk * NBUCK + t] = hist[t];
}

__global__ __launch_bounds__(512) void colscan(const int* __restrict__ blockHist,
                                               int* __restrict__ blockBaseCol,
                                               int* __restrict__ bucket_total) {
  __shared__ int s[512];
  int b = blockIdx.x, t = threadIdx.x;
  int v = (t < EBLK) ? blockHist[t * NBUCK + b] : 0;
  s[t] = v;
  __syncthreads();
  for (int off = 1; off < 512; off <<= 1) {
    int u = (t >= off) ? s[t - off] : 0;
    __syncthreads();
    s[t] += u;
    __syncthreads();
  }
  if (t < EBLK) blockBaseCol[b * EBLK + t] = s[t] - v;
  if (t == 511) bucket_total[b] = s[511];
}

__global__ __launch_bounds__(128) void bscan(const int* __restrict__ bucket_total,
                                             int* __restrict__ bucket_ptr) {
  __shared__ int s[128];
  int t = threadIdx.x;
  int v = (t < NBUCK) ? bucket_total[t] : 0;
  s[t] = v;
  __syncthreads();
  for (int off = 1; off < 128; off <<= 1) {
    int u = (t >= off) ? s[t - off] : 0;
    __syncthreads();
    s[t] += u;
    __syncthreads();
  }
  if (t < NBUCK) bucket_ptr[t] = s[t] - v;
  if (t == 127) bucket_ptr[NBUCK] = s[127];
}

// staging entry: (dst_local_10bits << 17) | src_17bits  (NNODES < 2^17)
__global__ __launch_bounds__(512) void bin_place(const int* __restrict__ esrc,
                                                 const int* __restrict__ edst,
                                                 const int* __restrict__ blockBaseCol,
                                                 const int* __restrict__ bucket_ptr,
                                                 unsigned* __restrict__ stagingG) {
  __shared__ int hist[NBUCK + 1], lbase[NBUCK + 1], lcur[NBUCK + 1], cbase[NBUCK];
  __shared__ int tmp[128];
  __shared__ uint2 st[EPB];
  int t = threadIdx.x, blk = blockIdx.x;
  if (t < NBUCK + 1) hist[t] = 0;
  __syncthreads();
  int e0 = blk * EPB;
#pragma unroll
  for (int it = 0; it < EPB / 512; ++it) {
    int e = e0 + it * 512 + t;
    int b = NBUCK;
    if (e < NEDGES) b = ((unsigned)edst[e]) >> 10;
    atomicAdd(&hist[b], 1);
  }
  __syncthreads();
  if (t < 128) tmp[t] = (t < NBUCK + 1) ? hist[t] : 0;
  __syncthreads();
  for (int off = 1; off < 128; off <<= 1) {
    int u = 0;
    if (t < 128 && t >= off) u = tmp[t - off];
    __syncthreads();
    if (t < 128) tmp[t] += u;
    __syncthreads();
  }
  if (t < NBUCK + 1) { int ex = tmp[t] - hist[t]; lbase[t] = ex; lcur[t] = ex; }
  if (t < NBUCK) cbase[t] = bucket_ptr[t] + blockBaseCol[t * EBLK + blk];
  __syncthreads();
#pragma unroll
  for (int it = 0; it < EPB / 512; ++it) {
    int e = e0 + it * 512 + t;
    unsigned s = 0, d = 0xFFFFFFFFu;
    if (e < NEDGES) { s = (unsigned)esrc[e]; d = (unsigned)edst[e]; }
    int b = (d == 0xFFFFFFFFu) ? NBUCK : (int)(d >> 10);
    int slot = atomicAdd(&lcur[b], 1);
    st[slot] = make_uint2(s, d);
  }
  __syncthreads();
  for (int i = t; i < EPB; i += 512) {
    uint2 ed = st[i];
    if (ed.y == 0xFFFFFFFFu) continue;
    int b = (int)(ed.y >> 10);
    stagingG[cbase[b] + (i - lbase[b])] = ((ed.y & 1023u) << 17) | ed.x;
  }
}

// fused: per-bucket degree histogram + LDS scan -> row_ptr, then scatter
__global__ __launch_bounds__(1024) void bucket_csr_fused(const unsigned* __restrict__ stagingG,
                                                         const int* __restrict__ bucket_ptr,
                                                         int* __restrict__ row_ptr,
                                                         int* __restrict__ colv) {
  __shared__ int dl[1024];
  __shared__ int cur[1024];
  int b = blockIdx.x, t = threadIdx.x;
  dl[t] = 0;
  __syncthreads();
  int s0 = bucket_ptr[b], s1 = bucket_ptr[b + 1];
  for (int j = s0 + t; j < s1; j += 1024)
    atomicAdd(&dl[stagingG[j] >> 17], 1);
  __syncthreads();
  int myDeg = dl[t];
  for (int off = 1; off < 1024; off <<= 1) {
    int u = (t >= off) ? dl[t - off] : 0;
    __syncthreads();
    dl[t] += u;
    __syncthreads();
  }
  int rp = s0 + dl[t] - myDeg;
  cur[t] = rp;
  int n = (b << 10) + t;
  if (n < NNODES) row_ptr[n] = rp;
  if (n == NNODES - 1) row_ptr[NNODES] = rp + myDeg;
  __syncthreads();
  for (int j = s0 + t; j < s1; j += 1024) {
    unsigned v = stagingG[j];
    int pos = atomicAdd(&cur[v >> 17], 1);
    colv[pos] = (int)(v & 0x1FFFFu);
  }
}

// ---------------- softmax aggregation: one wave per dst node -----------------
// fp8 payload (128B/row); weights broadcast via wave-private LDS ds_read_b64;
// both heads unpacked with one v_cvt_pk_f32_fp8; gather unrolled 8-deep.
__global__ __launch_bounds__(256) void aggregate(const unsigned short* __restrict__ hwb,
                                                 const float* __restrict__ a_s,
                                                 const float* __restrict__ a_d,
                                                 const int* __restrict__ row_ptr,
                                                 const int* __restrict__ colv,
                                                 const float* __restrict__ bias,
                                                 unsigned short* __restrict__ out) {
  __shared__ float2 wsh[256];           // 4 waves x 64 (w0,w1) entries
  int i = (blockIdx.x * 256 + threadIdx.x) >> 6;
  int lane = threadIdx.x & 63;
  if (i >= NNODES) return;
  i = __builtin_amdgcn_readfirstlane(i);
  int wbase = (threadIdx.x >> 6) * 64;

  float ad0 = a_d[2 * i], ad1 = a_d[2 * i + 1];
  int start = row_ptr[i], end = row_ptr[i + 1];
  int deg = end - start;
  float ws0 = __expf(lrelu(a_s[2 * i] + ad0));      // self edge
  float ws1 = __expf(lrelu(a_s[2 * i + 1] + ad1));

  int sl = 0; float w0l = 0.f, w1l = 0.f;
  if (lane < deg) {
    sl = colv[start + lane];
    float2 av = *reinterpret_cast<const float2*>(&a_s[2 * sl]);
    w0l = __expf(lrelu(av.x + ad0));
    w1l = __expf(lrelu(av.y + ad1));
  }
  wsh[wbase + lane] = make_float2(w0l, w1l);   // wave-private, no barrier
  float d0 = w0l, d1 = w1l;
  for (int o = 32; o; o >>= 1) { d0 += __shfl_xor(d0, o); d1 += __shfl_xor(d1, o); }
  float den0 = d0 + ws0, den1 = d1 + ws1;

  unsigned ps = hwb[(size_t)i * 64 + lane];
  f2v pv = pk_unpack_fp8(ps);
  float acc0 = ws0 * pv.x, acc1 = ws1 * pv.y;

  int dmin = deg < 64 ? deg : 64;
  int t = 0;
#define GSTEP(T)                                                               \
  {                                                                            \
    int s = __builtin_amdgcn_readlane(sl, (T));                                \
    unsigned q = hwb[(size_t)s * 64 + lane];                                   \
    float2 w = wsh[wbase + (T)];            /* ds_read_b64 broadcast */        \
    f2v xv = pk_unpack_fp8(q);                                                 \
    acc0 = fmaf(w.x, xv.x, acc0);                                              \
    acc1 = fmaf(w.y, xv.y, acc1);                                              \
  }
  for (; t + 8 <= dmin; t += 8) {
    GSTEP(t);     GSTEP(t + 1); GSTEP(t + 2); GSTEP(t + 3);
    GSTEP(t + 4); GSTEP(t + 5); GSTEP(t + 6); GSTEP(t + 7);
  }
  for (; t < dmin; ++t) { GSTEP(t); }
#undef GSTEP

  for (int j = start + 64; j < end; ++j) {   // rare overflow path (deg > 64)
    int s = colv[j];
    float2 av = *reinterpret_cast<const float2*>(&a_s[2 * s]);
    float w0 = __expf(lrelu(av.x + ad0));
    float w1 = __expf(lrelu(av.y + ad1));
    den0 += w0; den1 += w1;
    unsigned q = hwb[(size_t)s * 64 + lane];
    f2v xv = pk_unpack_fp8(q);
    acc0 = fmaf(w0, xv.x, acc0);
    acc1 = fmaf(w1, xv.y, acc1);
  }

  float r0 = fast_rcp(den0), r1 = fast_rcp(den1);
  float o0 = fmaxf(acc0 * r0 + bias[lane], 0.f);
  float o1 = fmaxf(acc1 * r1 + bias[64 + lane], 0.f);
  unsigned pk = cvt_pk_bf16(o0, o1);
  out[(size_t)i * 128 + lane]      = (unsigned short)pk;
  out[(size_t)i * 128 + 64 + lane] = (unsigned short)(pk >> 16);
}

// ---------------- per-graph pooling, node-parallel (bf16 input) --------------
#define SEG_CHUNK 128
__global__ __launch_bounds__(128) void seg_sum_fast(const unsigned short* __restrict__ h,
                                                    const int* __restrict__ batch,
                                                    const int* __restrict__ gstart,
                                                    float* __restrict__ reprs) {
  int n0 = blockIdx.x * SEG_CHUNK;
  if (n0 >= NNODES) return;
  int nend = n0 + SEG_CHUNK; if (nend > NNODES) nend = NNODES;
  int tid = threadIdx.x;
  int r = n0;
  while (r < nend) {
    int g = batch[r];
    int segend = gstart[g + 1]; if (segend > nend) segend = nend;
    float a0 = 0.f, a1 = 0.f, a2 = 0.f, a3 = 0.f;
    for (; r + 3 < segend; r += 4) {
      a0 += bf2f(h[(size_t)r * 128 + tid]);
      a1 += bf2f(h[(size_t)(r + 1) * 128 + tid]);
      a2 += bf2f(h[(size_t)(r + 2) * 128 + tid]);
      a3 += bf2f(h[(size_t)(r + 3) * 128 + tid]);
    }
    for (; r < segend; ++r) a0 += bf2f(h[(size_t)r * 128 + tid]);
    atomicAdd(&reprs[g * 128 + tid], (a0 + a1) + (a2 + a3));
  }
}

// ---------------- head MLP + log_softmax -------------------------------------
__global__ __launch_bounds__(128) void head_kernel(const float* __restrict__ reprs,
                                                   const float* __restrict__ pw1,
                                                   const float* __restrict__ pb1,
                                                   const float* __restrict__ pw2,
                                                   const float* __restrict__ pb2,
                                                   float* __restrict__ out) {
  __shared__ float r[128], t1[128], z[NCLS];
  int g = blockIdx.x, tid = threadIdx.x;
  r[tid] = reprs[g * 128 + tid];
  __syncthreads();
  float acc = pb1[tid];
  for (int k = 0; k < 128; ++k) acc = fmaf(r[k], pw1[k * 128 + tid], acc);
  t1[tid] = fmaxf(acc, 0.f);
  __syncthreads();
  if (tid < NCLS) {
    float zz = pb2[tid];
    for (int k = 0; k < 128; ++k) zz = fmaf(t1[k], pw2[k * NCLS + tid], zz);
    z[tid] = zz;
  }
  __syncthreads();
  if (tid == 0) {
    float mx = -1e30f;
    for (int c = 0; c < NCLS; ++c) mx = fmaxf(mx, z[c]);
    float s = 0.f;
    for (int c = 0; c < NCLS; ++c) s += expf(z[c] - mx);
    float ls = logf(s) + mx;
    for (int c = 0; c < NCLS; ++c) out[g * NCLS + c] = z[c] - ls;
  }
}

extern "C" void kernel_launch(void* const* d_in, const int* in_sizes, int n_in,
                              void* d_out, int out_size, void* d_ws, size_t ws_size,
                              hipStream_t stream) {
  const float* x     = (const float*)d_in[0];
  const int*   eidx  = (const int*)d_in[1];
  const int*   batch = (const int*)d_in[2];
  const float* pre_w = (const float*)d_in[3];
  const float* pre_b = (const float*)d_in[4];
  const float* w1    = (const float*)d_in[5];
  const float* asrc1 = (const float*)d_in[6];
  const float* adst1 = (const float*)d_in[7];
  const float* b1    = (const float*)d_in[8];
  const float* w2    = (const float*)d_in[9];
  const float* asrc2 = (const float*)d_in[10];
  const float* adst2 = (const float*)d_in[11];
  const float* b2    = (const float*)d_in[12];
  const float* pw1   = (const float*)d_in[13];
  const float* pb1   = (const float*)d_in[14];
  const float* pw2   = (const float*)d_in[15];
  const float* pb2   = (const float*)d_in[16];
  float* out = (float*)d_out;

  const int* esrc = eidx;
  const int* edst = eidx + NEDGES;

  char* wsp = (char*)d_ws;
  size_t off = 0;
  auto alloc = [&](size_t bytes) -> void* {
    void* p = wsp + off;
    off += (bytes + 255) & ~(size_t)255;
    return p;
  };
  unsigned short* hb  = (unsigned short*)alloc((size_t)NNODES * 128 * 2);
  unsigned short* hwb = (unsigned short*)alloc((size_t)NNODES * 64 * 2);   // fp8 pairs
  float* a_s         = (float*)alloc((size_t)NNODES * 2 * 4);
  float* a_d         = (float*)alloc((size_t)NNODES * 2 * 4);
  float* reprs       = (float*)alloc((size_t)NGRAPH * 128 * 4);
  int* gstart        = (int*)alloc((NGRAPH + 1) * 4);
  int* row_ptr       = (int*)alloc(((size_t)NNODES + 1) * 4);
  int* colv          = (int*)alloc((size_t)NEDGES * 4);
  unsigned short* wt_pre = (unsigned short*)alloc((size_t)128 * FIN * 2);
  unsigned short* wt1    = (unsigned short*)alloc((size_t)128 * HDIM * 2);
  unsigned short* wt2    = (unsigned short*)alloc((size_t)128 * HDIM * 2);
  int* blockHist     = (int*)alloc((size_t)EBLK * NBUCK * 4);
  int* blockBaseCol  = (int*)alloc((size_t)NBUCK * EBLK * 4);
  int* bucket_total  = (int*)alloc(NBUCK * 4);
  int* bucket_ptr    = (int*)alloc((NBUCK + 1) * 4);
  unsigned* stagingG = (unsigned*)alloc((size_t)NEDGES * 4);

  int wb = NNODES / 4;             // wave-per-node kernels: 256 thr = 4 waves
  int sb = (NNODES + SEG_CHUNK - 1) / SEG_CHUNK;
  int gb = (NNODES + 63) / 64;     // 1563 GEMM blocks (64-row tiles)

  // one-shot weight conversion (bf16, transposed)
  convert_transpose<<<(FIN * 128 + 255) / 256, 256, 0, stream>>>(pre_w, wt_pre, FIN);
  convert_transpose<<<(HDIM * 128 + 255) / 256, 256, 0, stream>>>(w1, wt1, HDIM);
  convert_transpose<<<(HDIM * 128 + 255) / 256, 256, 0, stream>>>(w2, wt2, HDIM);

  // graph boundaries + zeroed pooling accumulator
  hipMemsetAsync(reprs, 0, (size_t)NGRAPH * 128 * 4, stream);
  find_starts<<<1, 256, 0, stream>>>(batch, gstart);

  // bucketed CSR build (packed 4B staging; fused deg-scan + scatter)
  bin_count<<<EBLK, 256, 0, stream>>>(edst, blockHist);
  colscan<<<NBUCK, 512, 0, stream>>>(blockHist, blockBaseCol, bucket_total);
  bscan<<<1, 128, 0, stream>>>(bucket_total, bucket_ptr);
  bin_place<<<EBLK, 512, 0, stream>>>(esrc, edst, blockBaseCol, bucket_ptr, stagingG);
  bucket_csr_fused<<<NBUCK, 1024, 0, stream>>>(stagingG, bucket_ptr, row_ptr, colv);

  // pre layer: h0 = relu(x @ pre_w + pre_b)  (bf16 h)
  gemm_cstage<FIN, 0><<<gb, 256, 0, stream>>>(x, wt_pre, pre_b, hb, nullptr,
                                              nullptr, nullptr, nullptr, nullptr, NNODES, 1);
  seg_sum_fast<<<sb, 128, 0, stream>>>(hb, batch, gstart, reprs);

  // GAT layer 1 (bf16 A; alpha fused into GEMM epilogue; fp8 value payload)
  gemm_cstage<HDIM, 1><<<gb, 256, 0, stream>>>(hb, wt1, nullptr, nullptr, hwb,
                                               asrc1, adst1, a_s, a_d, NNODES, 0);
  aggregate<<<wb, 256, 0, stream>>>(hwb, a_s, a_d, row_ptr, colv, b1, hb);
  seg_sum_fast<<<sb, 128, 0, stream>>>(hb, batch, gstart, reprs);

  // GAT layer 2
  gemm_cstage<HDIM, 1><<<gb, 256, 0, stream>>>(hb, wt2, nullptr, nullptr, hwb,
                                               asrc2, adst2, a_s, a_d, NNODES, 0);
  aggregate<<<wb, 256, 0, stream>>>(hwb, a_s, a_d, row_ptr, colv, b2, hb);
  seg_sum_fast<<<sb, 128, 0, stream>>>(hb, batch, gstart, reprs);

  // head
  head_kernel<<<NGRAPH, 128, 0, stream>>>(reprs, pw1, pb1, pw2, pb2, out);
}

// Round 7
// 467.835 us; speedup vs baseline: 1.0252x; 1.0052x over previous
//
#include <hip/hip_runtime.h>
#include <hip/hip_bf16.h>
#include <math.h>

#define NNODES 100000
#define NEDGES 1600000
#define FIN 256
#define HDIM 128
#define NGRAPH 128
#define NCLS 10
#define NEG 0.2f

#define NBUCK 98            // buckets of 1024 dst nodes
#define EPB 4096            // edges per bin_place block
#define EBLK ((NEDGES + EPB - 1) / EPB)   // 391

typedef short bf8 __attribute__((ext_vector_type(8)));
typedef float f4 __attribute__((ext_vector_type(4)));
typedef float f2v __attribute__((ext_vector_type(2)));

__device__ __forceinline__ float lrelu(float x) { return x > 0.f ? x : NEG * x; }

__device__ __forceinline__ unsigned short f2bf(float f) {
  union { float f; unsigned int u; } v; v.f = f;
  unsigned int r = v.u + 0x7fffu + ((v.u >> 16) & 1u);   // round-nearest-even
  return (unsigned short)(r >> 16);
}
__device__ __forceinline__ float bf2f(unsigned short u) {
  union { unsigned int u; float f; } v; v.u = ((unsigned int)u) << 16; return v.f;
}
__device__ __forceinline__ float fast_rcp(float x) {
  float r;
  asm("v_rcp_f32 %0, %1" : "=v"(r) : "v"(x));
  return r;
}
__device__ __forceinline__ unsigned cvt_pk_bf16(float lo, float hi) {
  unsigned r;
  asm("v_cvt_pk_bf16_f32 %0, %1, %2" : "=v"(r) : "v"(lo), "v"(hi));
  return r;
}
// fp8 e4m3 (OCP, gfx950 native) pack/unpack: value payload for the gather.
__device__ __forceinline__ unsigned short pk_fp8(float a, float b) {
  return (unsigned short)__builtin_amdgcn_cvt_pk_fp8_f32(a, b, 0, false);
}
// one-instruction unpack of both heads: v_cvt_pk_f32_fp8 (bytes 0,1 -> 2x f32)
__device__ __forceinline__ f2v pk_unpack_fp8(unsigned p) {
#if __has_builtin(__builtin_amdgcn_cvt_pk_f32_fp8)
  return __builtin_amdgcn_cvt_pk_f32_fp8((int)p, false);
#else
  f2v r;
  r.x = __builtin_amdgcn_cvt_f32_fp8(p, 0);
  r.y = __builtin_amdgcn_cvt_f32_fp8(p, 1);
  return r;
#endif
}
// direct global->LDS DMA, 16B/lane: dest = wave-uniform base + lane*16,
// global src is PER-LANE (pre-swizzled addresses, linear LDS dest).
__device__ __forceinline__ void gload16(const void* gp, void* lp) {
  __builtin_amdgcn_global_load_lds(
      (const __attribute__((address_space(1))) void*)gp,
      (__attribute__((address_space(3))) void*)lp, 16, 0, 0);
}

// ---------------- one-shot weight convert+transpose: w[K][128] -> wt[128][K] -
__global__ __launch_bounds__(256) void convert_transpose(const float* __restrict__ w,
                                                         unsigned short* __restrict__ wt,
                                                         int K) {
  int i = blockIdx.x * 256 + threadIdx.x;
  if (i >= K * 128) return;
  int k = i >> 7, n = i & 127;
  wt[n * K + k] = f2bf(w[(size_t)k * 128 + n]);
}

// ---------------- MFMA GEMM: global_load_lds double-buffer, 64x128 tile ------
// R3-R6 post-mortem: all register-round-trip staging variants sat 62-81us with
// ~95% idle -- in-flight depth per wave capped by VGPR shuttling + vmcnt(0)
// drain per K-step. Fix = the one untried guide technique: width-16
// global_load_lds (no VGPR round trip, fire-and-forget LDS writes). Blob
// layout chosen so each DMA is exactly {uniform LDS base + lane*16}: per-lane
// global addr = MFMA fragment element, LDS stays linear. Double-buffered
// (24/32KB), ONE __syncthreads per 32-K step (its implicit vmcnt(0) drain is
// the correctness fence); stage of tile k+1 issued before compute of tile k.
// f32 A (pre-layer): staged raw, converted at fragment-read (cvt_pk_bf16 x4).
template<int K, int ABF16>
__global__ __launch_bounds__(256) void gemm_gll(const void* __restrict__ Av,
                                                const unsigned short* __restrict__ Bt,
                                                const float* __restrict__ bias,
                                                unsigned short* __restrict__ Cb,
                                                unsigned short* __restrict__ Cp,
                                                const float* __restrict__ a_src,
                                                const float* __restrict__ a_dst,
                                                float* __restrict__ o_as,
                                                float* __restrict__ o_ad,
                                                int M, int dorelu) {
  constexpr int ABUF = ABF16 ? 4096 : 8192;
  constexpr int SPAN = ABUF + 8192;
  __shared__ alignas(16) char lds[2 * SPAN];
  int tid = threadIdx.x;
  int wv = tid >> 6, lane = tid & 63;
  int quad = lane >> 4, m16 = lane & 15;
  int row0 = blockIdx.x * 64;
  int rA = row0 + wv * 16 + m16; if (rA > M - 1) rA = M - 1;
  int nB0 = wv * 16 + m16, nB1 = (4 + wv) * 16 + m16;

  const unsigned short* Ab = (const unsigned short*)Av;
  const float* Af = (const float*)Av;

  auto stage = [&](int buf, int kb) {
    char* base = lds + buf * SPAN;
    if (ABF16) {
      // A blob [mtile=wv][lane]: lane <- A[row0+wv*16+(lane&15)][kb+quad*8 ..+8]
      gload16(&Ab[(size_t)rA * K + kb + quad * 8], base + wv * 1024);
    } else {
      gload16(&Af[(size_t)rA * K + kb + quad * 8],     base + wv * 2048);
      gload16(&Af[(size_t)rA * K + kb + quad * 8 + 4], base + wv * 2048 + 1024);
    }
    char* bb = base + ABUF;
    gload16(&Bt[(size_t)nB0 * K + kb + quad * 8], bb + wv * 1024);
    gload16(&Bt[(size_t)nB1 * K + kb + quad * 8], bb + (4 + wv) * 1024);
  };

  f4 acc[8];
#pragma unroll
  for (int b = 0; b < 8; ++b) acc[b] = (f4){0.f, 0.f, 0.f, 0.f};

  stage(0, 0);
  int cur = 0;
#pragma unroll
  for (int kb = 0; kb < K; kb += 32) {
    __syncthreads();                       // drains stage(cur) + prev reads
    if (kb + 32 < K) stage(cur ^ 1, kb + 32);
    const char* base = lds + cur * SPAN;
    bf8 af;
    if (ABF16) {
      af = *(const bf8*)(base + wv * 1024 + lane * 16);
    } else {
      float4 x0 = *(const float4*)(base + wv * 2048 + lane * 16);
      float4 x1 = *(const float4*)(base + wv * 2048 + 1024 + lane * 16);
      union { bf8 v; unsigned u[4]; } r;
      r.u[0] = cvt_pk_bf16(x0.x, x0.y); r.u[1] = cvt_pk_bf16(x0.z, x0.w);
      r.u[2] = cvt_pk_bf16(x1.x, x1.y); r.u[3] = cvt_pk_bf16(x1.z, x1.w);
      af = r.v;
    }
    const char* bb = base + ABUF;
#pragma unroll
    for (int tn = 0; tn < 8; ++tn) {
      bf8 bm = *(const bf8*)(bb + tn * 1024 + lane * 16);
      acc[tn] = __builtin_amdgcn_mfma_f32_16x16x32_bf16(af, bm, acc[tn], 0, 0, 0);
    }
    cur ^= 1;
  }

  if (Cp) {
    if (a_src) {
      float aS[8], aD[8];
#pragma unroll
      for (int tn = 0; tn < 4; ++tn) {
        aS[tn]     = a_src[tn * 16 + m16];
        aS[tn + 4] = a_src[64 + tn * 16 + m16];
        aD[tn]     = a_dst[tn * 16 + m16];
        aD[tn + 4] = a_dst[64 + tn * 16 + m16];
      }
#pragma unroll
      for (int r = 0; r < 4; ++r) {
        int row = row0 + wv * 16 + quad * 4 + r;
        float ps0 = 0.f, ps1 = 0.f, pd0 = 0.f, pd1 = 0.f;
#pragma unroll
        for (int tn = 0; tn < 4; ++tn) {
          float v0 = acc[tn][r], v1 = acc[tn + 4][r];
          ps0 = fmaf(v0, aS[tn], ps0);
          ps1 = fmaf(v1, aS[tn + 4], ps1);
          pd0 = fmaf(v0, aD[tn], pd0);
          pd1 = fmaf(v1, aD[tn + 4], pd1);
        }
#pragma unroll
        for (int o = 8; o; o >>= 1) {
          ps0 += __shfl_xor(ps0, o); ps1 += __shfl_xor(ps1, o);
          pd0 += __shfl_xor(pd0, o); pd1 += __shfl_xor(pd1, o);
        }
        if (m16 == 0 && row < M) {
          o_as[2 * row] = ps0; o_as[2 * row + 1] = ps1;
          o_ad[2 * row] = pd0; o_ad[2 * row + 1] = pd1;
        }
      }
    }
#pragma unroll
    for (int tn = 0; tn < 4; ++tn)
#pragma unroll
      for (int r = 0; r < 4; ++r) {
        int row = row0 + wv * 16 + quad * 4 + r;
        if (row < M) {
          Cp[(size_t)row * 64 + tn * 16 + m16] = pk_fp8(acc[tn][r], acc[tn + 4][r]);
        }
      }
  } else {
#pragma unroll
    for (int tn = 0; tn < 8; ++tn) {
      float bv = bias ? bias[tn * 16 + m16] : 0.f;
#pragma unroll
      for (int r = 0; r < 4; ++r) {
        int row = row0 + wv * 16 + quad * 4 + r;
        if (row < M) {
          float v = acc[tn][r] + bv;
          if (dorelu) v = fmaxf(v, 0.f);
          Cb[(size_t)row * 128 + tn * 16 + m16] = f2bf(v);
        }
      }
    }
  }
}

// ---------------- graph boundaries (batch is sorted) -------------------------
__global__ void find_starts(const int* __restrict__ batch, int* __restrict__ gstart) {
  int g = threadIdx.x;
  if (g > NGRAPH) return;
  if (g == NGRAPH) { gstart[g] = NNODES; return; }
  int lo = 0, hi = NNODES;
  while (lo < hi) { int mid = (lo + hi) >> 1; if (batch[mid] < g) lo = mid + 1; else hi = mid; }
  gstart[g] = lo;
}

// ======== CSR build, bucketed two-phase (no random global atomics) ==========
__global__ __launch_bounds__(256) void bin_count(const int* __restrict__ edst,
                                                 int* __restrict__ blockHist) {
  __shared__ int hist[NBUCK];
  int t = threadIdx.x, blk = blockIdx.x;
  if (t < NBUCK) hist[t] = 0;
  __syncthreads();
  int e0 = blk * EPB;
#pragma unroll
  for (int it = 0; it < EPB / 256; ++it) {
    int e = e0 + it * 256 + t;
    if (e < NEDGES) atomicAdd(&hist[((unsigned)edst[e]) >> 10], 1);
  }
  __syncthreads();
  if (t < NBUCK) blockHist[blk * NBUCK + t] = hist[t];
}

__global__ __launch_bounds__(512) void colscan(const int* __restrict__ blockHist,
                                               int* __restrict__ blockBaseCol,
                                               int* __restrict__ bucket_total) {
  __shared__ int s[512];
  int b = blockIdx.x, t = threadIdx.x;
  int v = (t < EBLK) ? blockHist[t * NBUCK + b] : 0;
  s[t] = v;
  __syncthreads();
  for (int off = 1; off < 512; off <<= 1) {
    int u = (t >= off) ? s[t - off] : 0;
    __syncthreads();
    s[t] += u;
    __syncthreads();
  }
  if (t < EBLK) blockBaseCol[b * EBLK + t] = s[t] - v;
  if (t == 511) bucket_total[b] = s[511];
}

__global__ __launch_bounds__(128) void bscan(const int* __restrict__ bucket_total,
                                             int* __restrict__ bucket_ptr) {
  __shared__ int s[128];
  int t = threadIdx.x;
  int v = (t < NBUCK) ? bucket_total[t] : 0;
  s[t] = v;
  __syncthreads();
  for (int off = 1; off < 128; off <<= 1) {
    int u = (t >= off) ? s[t - off] : 0;
    __syncthreads();
    s[t] += u;
    __syncthreads();
  }
  if (t < NBUCK) bucket_ptr[t] = s[t] - v;
  if (t == 127) bucket_ptr[NBUCK] = s[127];
}

// staging entry: (dst_local_10bits << 17) | src_17bits  (NNODES < 2^17)
__global__ __launch_bounds__(512) void bin_place(const int* __restrict__ esrc,
                                                 const int* __restrict__ edst,
                                                 const int* __restrict__ blockBaseCol,
                                                 const int* __restrict__ bucket_ptr,
                                                 unsigned* __restrict__ stagingG) {
  __shared__ int hist[NBUCK + 1], lbase[NBUCK + 1], lcur[NBUCK + 1], cbase[NBUCK];
  __shared__ int tmp[128];
  __shared__ uint2 st[EPB];
  int t = threadIdx.x, blk = blockIdx.x;
  if (t < NBUCK + 1) hist[t] = 0;
  __syncthreads();
  int e0 = blk * EPB;
#pragma unroll
  for (int it = 0; it < EPB / 512; ++it) {
    int e = e0 + it * 512 + t;
    int b = NBUCK;
    if (e < NEDGES) b = ((unsigned)edst[e]) >> 10;
    atomicAdd(&hist[b], 1);
  }
  __syncthreads();
  if (t < 128) tmp[t] = (t < NBUCK + 1) ? hist[t] : 0;
  __syncthreads();
  for (int off = 1; off < 128; off <<= 1) {
    int u = 0;
    if (t < 128 && t >= off) u = tmp[t - off];
    __syncthreads();
    if (t < 128) tmp[t] += u;
    __syncthreads();
  }
  if (t < NBUCK + 1) { int ex = tmp[t] - hist[t]; lbase[t] = ex; lcur[t] = ex; }
  if (t < NBUCK) cbase[t] = bucket_ptr[t] + blockBaseCol[t * EBLK + blk];
  __syncthreads();
#pragma unroll
  for (int it = 0; it < EPB / 512; ++it) {
    int e = e0 + it * 512 + t;
    unsigned s = 0, d = 0xFFFFFFFFu;
    if (e < NEDGES) { s = (unsigned)esrc[e]; d = (unsigned)edst[e]; }
    int b = (d == 0xFFFFFFFFu) ? NBUCK : (int)(d >> 10);
    int slot = atomicAdd(&lcur[b], 1);
    st[slot] = make_uint2(s, d);
  }
  __syncthreads();
  for (int i = t; i < EPB; i += 512) {
    uint2 ed = st[i];
    if (ed.y == 0xFFFFFFFFu) continue;
    int b = (int)(ed.y >> 10);
    stagingG[cbase[b] + (i - lbase[b])] = ((ed.y & 1023u) << 17) | ed.x;
  }
}

// fused: per-bucket degree histogram + LDS scan -> row_ptr, then scatter
__global__ __launch_bounds__(1024) void bucket_csr_fused(const unsigned* __restrict__ stagingG,
                                                         const int* __restrict__ bucket_ptr,
                                                         int* __restrict__ row_ptr,
                                                         int* __restrict__ colv) {
  __shared__ int dl[1024];
  __shared__ int cur[1024];
  int b = blockIdx.x, t = threadIdx.x;
  dl[t] = 0;
  __syncthreads();
  int s0 = bucket_ptr[b], s1 = bucket_ptr[b + 1];
  for (int j = s0 + t; j < s1; j += 1024)
    atomicAdd(&dl[stagingG[j] >> 17], 1);
  __syncthreads();
  int myDeg = dl[t];
  for (int off = 1; off < 1024; off <<= 1) {
    int u = (t >= off) ? dl[t - off] : 0;
    __syncthreads();
    dl[t] += u;
    __syncthreads();
  }
  int rp = s0 + dl[t] - myDeg;
  cur[t] = rp;
  int n = (b << 10) + t;
  if (n < NNODES) row_ptr[n] = rp;
  if (n == NNODES - 1) row_ptr[NNODES] = rp + myDeg;
  __syncthreads();
  for (int j = s0 + t; j < s1; j += 1024) {
    unsigned v = stagingG[j];
    int pos = atomicAdd(&cur[v >> 17], 1);
    colv[pos] = (int)(v & 0x1FFFFu);
  }
}

// ---------------- softmax aggregation: one wave per dst node -----------------
// fp8 payload (128B/row); weights broadcast via wave-private LDS ds_read_b64;
// both heads unpacked with one v_cvt_pk_f32_fp8; gather unrolled 8-deep.
__global__ __launch_bounds__(256) void aggregate(const unsigned short* __restrict__ hwb,
                                                 const float* __restrict__ a_s,
                                                 const float* __restrict__ a_d,
                                                 const int* __restrict__ row_ptr,
                                                 const int* __restrict__ colv,
                                                 const float* __restrict__ bias,
                                                 unsigned short* __restrict__ out) {
  __shared__ float2 wsh[256];           // 4 waves x 64 (w0,w1) entries
  int i = (blockIdx.x * 256 + threadIdx.x) >> 6;
  int lane = threadIdx.x & 63;
  if (i >= NNODES) return;
  i = __builtin_amdgcn_readfirstlane(i);
  int wbase = (threadIdx.x >> 6) * 64;

  float ad0 = a_d[2 * i], ad1 = a_d[2 * i + 1];
  int start = row_ptr[i], end = row_ptr[i + 1];
  int deg = end - start;
  float ws0 = __expf(lrelu(a_s[2 * i] + ad0));      // self edge
  float ws1 = __expf(lrelu(a_s[2 * i + 1] + ad1));

  int sl = 0; float w0l = 0.f, w1l = 0.f;
  if (lane < deg) {
    sl = colv[start + lane];
    float2 av = *reinterpret_cast<const float2*>(&a_s[2 * sl]);
    w0l = __expf(lrelu(av.x + ad0));
    w1l = __expf(lrelu(av.y + ad1));
  }
  wsh[wbase + lane] = make_float2(w0l, w1l);   // wave-private, no barrier
  float d0 = w0l, d1 = w1l;
  for (int o = 32; o; o >>= 1) { d0 += __shfl_xor(d0, o); d1 += __shfl_xor(d1, o); }
  float den0 = d0 + ws0, den1 = d1 + ws1;

  unsigned ps = hwb[(size_t)i * 64 + lane];
  f2v pv = pk_unpack_fp8(ps);
  float acc0 = ws0 * pv.x, acc1 = ws1 * pv.y;

  int dmin = deg < 64 ? deg : 64;
  int t = 0;
#define GSTEP(T)                                                               \
  {                                                                            \
    int s = __builtin_amdgcn_readlane(sl, (T));                                \
    unsigned q = hwb[(size_t)s * 64 + lane];                                   \
    float2 w = wsh[wbase + (T)];            /* ds_read_b64 broadcast */        \
    f2v xv = pk_unpack_fp8(q);                                                 \
    acc0 = fmaf(w.x, xv.x, acc0);                                              \
    acc1 = fmaf(w.y, xv.y, acc1);                                              \
  }
  for (; t + 8 <= dmin; t += 8) {
    GSTEP(t);     GSTEP(t + 1); GSTEP(t + 2); GSTEP(t + 3);
    GSTEP(t + 4); GSTEP(t + 5); GSTEP(t + 6); GSTEP(t + 7);
  }
  for (; t < dmin; ++t) { GSTEP(t); }
#undef GSTEP

  for (int j = start + 64; j < end; ++j) {   // rare overflow path (deg > 64)
    int s = colv[j];
    float2 av = *reinterpret_cast<const float2*>(&a_s[2 * s]);
    float w0 = __expf(lrelu(av.x + ad0));
    float w1 = __expf(lrelu(av.y + ad1));
    den0 += w0; den1 += w1;
    unsigned q = hwb[(size_t)s * 64 + lane];
    f2v xv = pk_unpack_fp8(q);
    acc0 = fmaf(w0, xv.x, acc0);
    acc1 = fmaf(w1, xv.y, acc1);
  }

  float r0 = fast_rcp(den0), r1 = fast_rcp(den1);
  float o0 = fmaxf(acc0 * r0 + bias[lane], 0.f);
  float o1 = fmaxf(acc1 * r1 + bias[64 + lane], 0.f);
  unsigned pk = cvt_pk_bf16(o0, o1);
  out[(size_t)i * 128 + lane]      = (unsigned short)pk;
  out[(size_t)i * 128 + 64 + lane] = (unsigned short)(pk >> 16);
}

// ---------------- per-graph pooling, node-parallel (bf16 input) --------------
#define SEG_CHUNK 128
__global__ __launch_bounds__(128) void seg_sum_fast(const unsigned short* __restrict__ h,
                                                    const int* __restrict__ batch,
                                                    const int* __restrict__ gstart,
                                                    float* __restrict__ reprs) {
  int n0 = blockIdx.x * SEG_CHUNK;
  if (n0 >= NNODES) return;
  int nend = n0 + SEG_CHUNK; if (nend > NNODES) nend = NNODES;
  int tid = threadIdx.x;
  int r = n0;
  while (r < nend) {
    int g = batch[r];
    int segend = gstart[g + 1]; if (segend > nend) segend = nend;
    float a0 = 0.f, a1 = 0.f, a2 = 0.f, a3 = 0.f;
    for (; r + 3 < segend; r += 4) {
      a0 += bf2f(h[(size_t)r * 128 + tid]);
      a1 += bf2f(h[(size_t)(r + 1) * 128 + tid]);
      a2 += bf2f(h[(size_t)(r + 2) * 128 + tid]);
      a3 += bf2f(h[(size_t)(r + 3) * 128 + tid]);
    }
    for (; r < segend; ++r) a0 += bf2f(h[(size_t)r * 128 + tid]);
    atomicAdd(&reprs[g * 128 + tid], (a0 + a1) + (a2 + a3));
  }
}

// ---------------- head MLP + log_softmax -------------------------------------
__global__ __launch_bounds__(128) void head_kernel(const float* __restrict__ reprs,
                                                   const float* __restrict__ pw1,
                                                   const float* __restrict__ pb1,
                                                   const float* __restrict__ pw2,
                                                   const float* __restrict__ pb2,
                                                   float* __restrict__ out) {
  __shared__ float r[128], t1[128], z[NCLS];
  int g = blockIdx.x, tid = threadIdx.x;
  r[tid] = reprs[g * 128 + tid];
  __syncthreads();
  float acc = pb1[tid];
  for (int k = 0; k < 128; ++k) acc = fmaf(r[k], pw1[k * 128 + tid], acc);
  t1[tid] = fmaxf(acc, 0.f);
  __syncthreads();
  if (tid < NCLS) {
    float zz = pb2[tid];
    for (int k = 0; k < 128; ++k) zz = fmaf(t1[k], pw2[k * NCLS + tid], zz);
    z[tid] = zz;
  }
  __syncthreads();
  if (tid == 0) {
    float mx = -1e30f;
    for (int c = 0; c < NCLS; ++c) mx = fmaxf(mx, z[c]);
    float s = 0.f;
    for (int c = 0; c < NCLS; ++c) s += expf(z[c] - mx);
    float ls = logf(s) + mx;
    for (int c = 0; c < NCLS; ++c) out[g * NCLS + c] = z[c] - ls;
  }
}

extern "C" void kernel_launch(void* const* d_in, const int* in_sizes, int n_in,
                              void* d_out, int out_size, void* d_ws, size_t ws_size,
                              hipStream_t stream) {
  const float* x     = (const float*)d_in[0];
  const int*   eidx  = (const int*)d_in[1];
  const int*   batch = (const int*)d_in[2];
  const float* pre_w = (const float*)d_in[3];
  const float* pre_b = (const float*)d_in[4];
  const float* w1    = (const float*)d_in[5];
  const float* asrc1 = (const float*)d_in[6];
  const float* adst1 = (const float*)d_in[7];
  const float* b1    = (const float*)d_in[8];
  const float* w2    = (const float*)d_in[9];
  const float* asrc2 = (const float*)d_in[10];
  const float* adst2 = (const float*)d_in[11];
  const float* b2    = (const float*)d_in[12];
  const float* pw1   = (const float*)d_in[13];
  const float* pb1   = (const float*)d_in[14];
  const float* pw2   = (const float*)d_in[15];
  const float* pb2   = (const float*)d_in[16];
  float* out = (float*)d_out;

  const int* esrc = eidx;
  const int* edst = eidx + NEDGES;

  char* wsp = (char*)d_ws;
  size_t off = 0;
  auto alloc = [&](size_t bytes) -> void* {
    void* p = wsp + off;
    off += (bytes + 255) & ~(size_t)255;
    return p;
  };
  unsigned short* hb  = (unsigned short*)alloc((size_t)NNODES * 128 * 2);
  unsigned short* hwb = (unsigned short*)alloc((size_t)NNODES * 64 * 2);   // fp8 pairs
  float* a_s         = (float*)alloc((size_t)NNODES * 2 * 4);
  float* a_d         = (float*)alloc((size_t)NNODES * 2 * 4);
  float* reprs       = (float*)alloc((size_t)NGRAPH * 128 * 4);
  int* gstart        = (int*)alloc((NGRAPH + 1) * 4);
  int* row_ptr       = (int*)alloc(((size_t)NNODES + 1) * 4);
  int* colv          = (int*)alloc((size_t)NEDGES * 4);
  unsigned short* wt_pre = (unsigned short*)alloc((size_t)128 * FIN * 2);
  unsigned short* wt1    = (unsigned short*)alloc((size_t)128 * HDIM * 2);
  unsigned short* wt2    = (unsigned short*)alloc((size_t)128 * HDIM * 2);
  int* blockHist     = (int*)alloc((size_t)EBLK * NBUCK * 4);
  int* blockBaseCol  = (int*)alloc((size_t)NBUCK * EBLK * 4);
  int* bucket_total  = (int*)alloc(NBUCK * 4);
  int* bucket_ptr    = (int*)alloc((NBUCK + 1) * 4);
  unsigned* stagingG = (unsigned*)alloc((size_t)NEDGES * 4);

  int wb = NNODES / 4;             // wave-per-node kernels: 256 thr = 4 waves
  int sb = (NNODES + SEG_CHUNK - 1) / SEG_CHUNK;
  int gb = (NNODES + 63) / 64;     // 1563 GEMM blocks (64-row tiles)

  // one-shot weight conversion (bf16, transposed)
  convert_transpose<<<(FIN * 128 + 255) / 256, 256, 0, stream>>>(pre_w, wt_pre, FIN);
  convert_transpose<<<(HDIM * 128 + 255) / 256, 256, 0, stream>>>(w1, wt1, HDIM);
  convert_transpose<<<(HDIM * 128 + 255) / 256, 256, 0, stream>>>(w2, wt2, HDIM);

  // graph boundaries + zeroed pooling accumulator
  hipMemsetAsync(reprs, 0, (size_t)NGRAPH * 128 * 4, stream);
  find_starts<<<1, 256, 0, stream>>>(batch, gstart);

  // bucketed CSR build (packed 4B staging; fused deg-scan + scatter)
  bin_count<<<EBLK, 256, 0, stream>>>(edst, blockHist);
  colscan<<<NBUCK, 512, 0, stream>>>(blockHist, blockBaseCol, bucket_total);
  bscan<<<1, 128, 0, stream>>>(bucket_total, bucket_ptr);
  bin_place<<<EBLK, 512, 0, stream>>>(esrc, edst, blockBaseCol, bucket_ptr, stagingG);
  bucket_csr_fused<<<NBUCK, 1024, 0, stream>>>(stagingG, bucket_ptr, row_ptr, colv);

  // pre layer: h0 = relu(x @ pre_w + pre_b)  (bf16 h)
  gemm_gll<FIN, 0><<<gb, 256, 0, stream>>>(x, wt_pre, pre_b, hb, nullptr,
                                           nullptr, nullptr, nullptr, nullptr, NNODES, 1);
  seg_sum_fast<<<sb, 128, 0, stream>>>(hb, batch, gstart, reprs);

  // GAT layer 1 (bf16 A; alpha fused into GEMM epilogue; fp8 value payload)
  gemm_gll<HDIM, 1><<<gb, 256, 0, stream>>>(hb, wt1, nullptr, nullptr, hwb,
                                            asrc1, adst1, a_s, a_d, NNODES, 0);
  aggregate<<<wb, 256, 0, stream>>>(hwb, a_s, a_d, row_ptr, colv, b1, hb);
  seg_sum_fast<<<sb, 128, 0, stream>>>(hb, batch, gstart, reprs);

  // GAT layer 2
  gemm_gll<HDIM, 1><<<gb, 256, 0, stream>>>(hb, wt2, nullptr, nullptr, hwb,
                                            asrc2, adst2, a_s, a_d, NNODES, 0);
  aggregate<<<wb, 256, 0, stream>>>(hwb, a_s, a_d, row_ptr, colv, b2, hb);
  seg_sum_fast<<<sb, 128, 0, stream>>>(hb, batch, gstart, reprs);

  // head
  head_kernel<<<NGRAPH, 128, 0, stream>>>(reprs, pw1, pb1, pw2, pb2, out);
}